// Round 2
// baseline (219.005 us; speedup 1.0000x reference)
//
#include <hip/hip_runtime.h>

// GNN1: drug-relation GNN layer, MI355X (gfx950).
//   b2sum_kernel : b2sum[k] = sum_e b2[k,e]                       (4 blocks)
//   fused_gnn    : per-drug block: w2sum, W1 hi/lo split -> LDS,
//                  split-bf16 MFMA GEMM (1024x64x64) w/ pipelined rela gather,
//                  +b1/relu/dot w2sum, softmax over K, weighted ent gather,
//                  final linear -> y (ws)
//   bn_kernel    : BatchNorm1d (training stats) over N=846 -> out  (64 blocks)

#define NDRUG 846
#define KNB   1024
#define BN_EPS 1e-5f

typedef __attribute__((ext_vector_type(8))) short short8;
typedef __attribute__((ext_vector_type(4))) float f32x4;

__device__ __forceinline__ unsigned short f2bf(float x){
    unsigned u = __float_as_uint(x);
    unsigned r = u + 0x7fffu + ((u >> 16) & 1u);
    return (unsigned short)(r >> 16);
}
__device__ __forceinline__ float bf2f(unsigned short h){
    return __uint_as_float(((unsigned)h) << 16);
}

__global__ void b2sum_kernel(const float* __restrict__ b2, float* __restrict__ b2s){
    int k = blockIdx.x*256 + threadIdx.x;
    const float4* p = (const float4*)(b2 + (size_t)k*64);
    float s = 0.f;
    #pragma unroll
    for (int i = 0; i < 16; ++i){ float4 v = p[i]; s += v.x+v.y+v.z+v.w; }
    b2s[k] = s;
}

__global__ __launch_bounds__(256,4) void fused_gnn(
    const float* __restrict__ drug_table, const float* __restrict__ rela_table,
    const float* __restrict__ ent_table,  const float* __restrict__ W1,
    const float* __restrict__ b1,         const float* __restrict__ W2,
    const float* __restrict__ lin_w,      const float* __restrict__ lin_b,
    const int* __restrict__ drug_name,    const int* __restrict__ adj_tail,
    const int* __restrict__ adj_rel,      const float* __restrict__ b2sum,
    float* __restrict__ y_out)
{
    __shared__ unsigned short Bh[4096], Bl[4096]; // W1 split, fragment-linear
    __shared__ float scores[KNB];
    __shared__ float w2s[64];
    __shared__ float drug[64];
    __shared__ float red[256];
    __shared__ float wepart[4][64];
    __shared__ float de[128];

    const int t = threadIdx.x;
    const int lane = t & 63;
    const int w = t >> 6;
    const int n = blockIdx.x;

    if (t < 64) drug[t] = drug_table[(size_t)drug_name[n]*64 + t];

    { // w2sum partials: thread t covers W2[n] floats [t*16, t*16+16)
        const float4* W2v = (const float4*)(W2 + (size_t)n*4096);
        float s = 0.f;
        #pragma unroll
        for (int i = 0; i < 4; ++i){ float4 v = W2v[t*4+i]; s += v.x+v.y+v.z+v.w; }
        red[t] = s;
    }
    __syncthreads();
    if (t < 64) w2s[t] = red[t*4]+red[t*4+1]+red[t*4+2]+red[t*4+3];

    { // stage W1 -> hi/lo bf16, fragment-linear layout for mfma_16x16x32 B-frags
        const float* W1n = W1 + (size_t)n*4096;
        #pragma unroll
        for (int p = 0; p < 16; ++p){
            int idx = p*256 + t;            // coalesced read: d = idx>>6, e = idx&63
            float v = W1n[idx];
            int d = idx >> 6, e = idx & 63;
            int ss = d >> 5, j = d & 7, lg = (d >> 3) & 3;
            int ln = (lg << 4) | (e & 15);
            int dst = (((ss<<2) | (e>>4))*64 + ln)*8 + j;
            unsigned short h = f2bf(v);
            Bh[dst] = h;
            Bl[dst] = f2bf(v - bf2f(h));
        }
    }
    __syncthreads();

    // per-lane drug values at this lane's fixed d-offsets
    float dreg[2][8];
    {
        int d0 = (lane >> 4) << 3;
        #pragma unroll
        for (int ss = 0; ss < 2; ++ss)
            #pragma unroll
            for (int j = 0; j < 8; ++j)
                dreg[ss][j] = drug[ss*32 + d0 + j];
    }

    const int* arel = adj_rel + (size_t)n*KNB;
    const int kw = w * 256;   // wave's k-range [kw, kw+256)

    f32x4 acc[2][4] = {};
    float4 raw[8];   // full 64-float rela rows for both m-tiles (static-indexed)

    // gather chunk kb's rela rows (one dependent chain per m-tile per chunk)
    #define LOADRAW(kb_) do {                                              \
        int r0_ = arel[(kb_) + (lane & 15)];                               \
        int r1_ = arel[(kb_) + 16 + (lane & 15)];                          \
        const float* p0_ = rela_table + (size_t)r0_*64 + ((lane>>4)<<3);   \
        const float* p1_ = rela_table + (size_t)r1_*64 + ((lane>>4)<<3);   \
        raw[0] = *(const float4*)p0_;      raw[1] = *(const float4*)(p0_+4);  \
        raw[2] = *(const float4*)(p0_+32); raw[3] = *(const float4*)(p0_+36); \
        raw[4] = *(const float4*)p1_;      raw[5] = *(const float4*)(p1_+4);  \
        raw[6] = *(const float4*)(p1_+32); raw[7] = *(const float4*)(p1_+36); \
    } while(0)

    // convert 8 raw floats (one m-tile, one ss half) into hi/lo bf16 A-frags
    #define CVT(va, vb, ss_, AH, AL) do {                                  \
        float xs_[8] = {(va).x,(va).y,(va).z,(va).w,(vb).x,(vb).y,(vb).z,(vb).w}; \
        _Pragma("unroll")                                                  \
        for (int j_ = 0; j_ < 8; ++j_){                                    \
            float x_ = xs_[j_] * dreg[ss_][j_];                            \
            unsigned short h_ = (unsigned short)(__float_as_uint(x_) >> 16); /* trunc hi */ \
            (AH)[j_] = (short)h_;                                          \
            (AL)[j_] = (short)f2bf(x_ - bf2f(h_));                         \
        }                                                                  \
    } while(0)

    LOADRAW(kw);

    #pragma unroll 1
    for (int c = 0; c < 8; ++c){
        const int kb = kw + c*32;          // 32 k-rows per chunk (2 M-tiles)
        short8 Ah0, Al0, Ah1, Al1;

        // ss = 0 (d: 0..31)
        CVT(raw[0], raw[1], 0, Ah0, Al0);
        CVT(raw[4], raw[5], 0, Ah1, Al1);
        #pragma unroll
        for (int nn = 0; nn < 4; ++nn){
            int fb = (nn*64 + lane)*8;
            short8 bh = *(const short8*)&Bh[fb];
            short8 bl = *(const short8*)&Bl[fb];
            acc[0][nn] = __builtin_amdgcn_mfma_f32_16x16x32_bf16(Ah0, bh, acc[0][nn], 0,0,0);
            acc[0][nn] = __builtin_amdgcn_mfma_f32_16x16x32_bf16(Ah0, bl, acc[0][nn], 0,0,0);
            acc[0][nn] = __builtin_amdgcn_mfma_f32_16x16x32_bf16(Al0, bh, acc[0][nn], 0,0,0);
            acc[1][nn] = __builtin_amdgcn_mfma_f32_16x16x32_bf16(Ah1, bh, acc[1][nn], 0,0,0);
            acc[1][nn] = __builtin_amdgcn_mfma_f32_16x16x32_bf16(Ah1, bl, acc[1][nn], 0,0,0);
            acc[1][nn] = __builtin_amdgcn_mfma_f32_16x16x32_bf16(Al1, bh, acc[1][nn], 0,0,0);
        }

        // ss = 1 (d: 32..63)
        CVT(raw[2], raw[3], 1, Ah0, Al0);
        CVT(raw[6], raw[7], 1, Ah1, Al1);
        if (c < 7) LOADRAW(kb + 32);   // raw regs dead: prefetch next chunk's gather
        #pragma unroll
        for (int nn = 0; nn < 4; ++nn){
            int fb = ((4+nn)*64 + lane)*8;
            short8 bh = *(const short8*)&Bh[fb];
            short8 bl = *(const short8*)&Bl[fb];
            acc[0][nn] = __builtin_amdgcn_mfma_f32_16x16x32_bf16(Ah0, bh, acc[0][nn], 0,0,0);
            acc[0][nn] = __builtin_amdgcn_mfma_f32_16x16x32_bf16(Ah0, bl, acc[0][nn], 0,0,0);
            acc[0][nn] = __builtin_amdgcn_mfma_f32_16x16x32_bf16(Al0, bh, acc[0][nn], 0,0,0);
            acc[1][nn] = __builtin_amdgcn_mfma_f32_16x16x32_bf16(Ah1, bh, acc[1][nn], 0,0,0);
            acc[1][nn] = __builtin_amdgcn_mfma_f32_16x16x32_bf16(Ah1, bl, acc[1][nn], 0,0,0);
            acc[1][nn] = __builtin_amdgcn_mfma_f32_16x16x32_bf16(Al1, bh, acc[1][nn], 0,0,0);
        }

        // epilogue: s[k] = sum_e relu(H + b1) * w2sum[e]  (prefetched gathers in flight)
        #pragma unroll
        for (int m = 0; m < 2; ++m){
            f32x4 sp = {0.f,0.f,0.f,0.f};
            int rbase = kb + m*16 + ((lane>>4)<<2);
            #pragma unroll
            for (int nn = 0; nn < 4; ++nn){
                int e = (nn<<4) | (lane & 15);
                float wv = w2s[e];
                #pragma unroll
                for (int q = 0; q < 4; ++q){
                    float h = acc[m][nn][q] + b1[(size_t)(rbase+q)*64 + e];
                    sp[q] += fmaxf(h, 0.f) * wv;
                }
                acc[m][nn] = (f32x4){0.f,0.f,0.f,0.f};   // reset for next chunk
            }
            #pragma unroll
            for (int off = 1; off < 16; off <<= 1){
                #pragma unroll
                for (int q = 0; q < 4; ++q)
                    sp[q] += __shfl_xor(sp[q], off, 64);
            }
            if ((lane & 15) == 0){
                #pragma unroll
                for (int q = 0; q < 4; ++q)
                    scores[rbase + q] = sp[q];
            }
        }
    }
    __syncthreads();

    // block softmax over 1024 scores (+ b2sum)
    float sv[4]; float mx = -1e30f;
    #pragma unroll
    for (int i = 0; i < 4; ++i){
        sv[i] = scores[t + i*256] + b2sum[t + i*256];
        mx = fmaxf(mx, sv[i]);
    }
    #pragma unroll
    for (int off = 1; off < 64; off <<= 1) mx = fmaxf(mx, __shfl_xor(mx, off, 64));
    if (lane == 0) red[w] = mx;
    __syncthreads();
    mx = fmaxf(fmaxf(red[0], red[1]), fmaxf(red[2], red[3]));
    float ps = 0.f;
    #pragma unroll
    for (int i = 0; i < 4; ++i){
        float e = __expf(sv[i] - mx);
        scores[t + i*256] = e;
        ps += e;
    }
    #pragma unroll
    for (int off = 1; off < 64; off <<= 1) ps += __shfl_xor(ps, off, 64);
    if (lane == 0) red[8 + w] = ps;
    __syncthreads();
    float inv = 1.f / (red[8]+red[9]+red[10]+red[11]);

    // weighted entity gather; skip exact-zero weights (exp underflow), wave-uniform
    const int* atail = adj_tail + (size_t)n*KNB;
    float awe = 0.f;
    for (int k = kw; k < kw + 256; ++k){
        float e = scores[k];
        if (e != 0.0f){
            int tl = atail[k];
            awe += e * ent_table[(size_t)tl*64 + lane];
        }
    }
    wepart[w][lane] = awe;
    __syncthreads();
    if (t < 64){
        de[t]    = (wepart[0][t]+wepart[1][t]+wepart[2][t]+wepart[3][t]) * inv;
        de[64+t] = drug[t];
    }
    __syncthreads();

    // y[j] = relu(lin_b[j] + sum_i de[i]*lin_w[j,i]); wave w covers i in [w*32, w*32+32)
    float yp = 0.f;
    #pragma unroll
    for (int ii = 0; ii < 32; ++ii){
        int i = w*32 + ii;
        yp += de[i] * lin_w[lane*128 + i];
    }
    red[t] = yp;
    __syncthreads();
    if (t < 64){
        float yv = lin_b[t] + red[t] + red[64+t] + red[128+t] + red[192+t];
        y_out[(size_t)n*64 + t] = fmaxf(yv, 0.f);
    }
}

__global__ void bn_kernel(const float* __restrict__ y, const float* __restrict__ bn_w,
                          const float* __restrict__ bn_b, float* __restrict__ out){
    __shared__ float r1[4], r2[4];
    const int j = blockIdx.x;
    const int t = threadIdx.x;
    float s1 = 0.f, s2 = 0.f;
    for (int i = t; i < NDRUG; i += 256){
        float v = y[(size_t)i*64 + j];
        s1 += v; s2 += v*v;
    }
    #pragma unroll
    for (int off = 1; off < 64; off <<= 1){
        s1 += __shfl_xor(s1, off, 64);
        s2 += __shfl_xor(s2, off, 64);
    }
    int w = t >> 6, lane = t & 63;
    if (lane == 0){ r1[w] = s1; r2[w] = s2; }
    __syncthreads();
    s1 = r1[0]+r1[1]+r1[2]+r1[3];
    s2 = r2[0]+r2[1]+r2[2]+r2[3];
    float mean = s1 * (1.f/NDRUG);
    float var  = s2 * (1.f/NDRUG) - mean*mean;   // biased (training-mode) variance
    float sc = rsqrtf(var + BN_EPS) * bn_w[j];
    float sh = bn_b[j] - mean*sc;
    for (int i = t; i < NDRUG; i += 256)
        out[(size_t)i*64 + j] = y[(size_t)i*64 + j]*sc + sh;
}

extern "C" void kernel_launch(void* const* d_in, const int* in_sizes, int n_in,
                              void* d_out, int out_size, void* d_ws, size_t ws_size,
                              hipStream_t stream) {
    const float* drug_table = (const float*)d_in[0];
    const float* rela_table = (const float*)d_in[1];
    const float* ent_table  = (const float*)d_in[2];
    const float* W1    = (const float*)d_in[3];
    const float* b1    = (const float*)d_in[4];
    const float* W2    = (const float*)d_in[5];
    const float* b2    = (const float*)d_in[6];
    const float* lin_w = (const float*)d_in[7];
    const float* lin_b = (const float*)d_in[8];
    const float* bn_w  = (const float*)d_in[9];
    const float* bn_b  = (const float*)d_in[10];
    const int* drug_name = (const int*)d_in[11];
    const int* adj_tail  = (const int*)d_in[12];
    const int* adj_rel   = (const int*)d_in[13];
    float* out = (float*)d_out;

    float* b2s = (float*)d_ws;          // [1024]
    float* yb  = b2s + KNB;             // [846*64]

    b2sum_kernel<<<KNB/256, 256, 0, stream>>>(b2, b2s);
    fused_gnn<<<NDRUG, 256, 0, stream>>>(drug_table, rela_table, ent_table, W1, b1, W2,
                                         lin_w, lin_b, drug_name, adj_tail, adj_rel, b2s, yb);
    bn_kernel<<<64, 256, 0, stream>>>(yb, bn_w, bn_b, out);
}

// Round 3
// 76.085 us; speedup vs baseline: 2.8784x; 2.8784x over previous
//
#include <hip/hip_runtime.h>

// GNN1: drug-relation GNN layer, MI355X (gfx950).
// Key insight: pre-bias hidden state depends only on (drug, relation) and
// there are only 200 relations -> per-drug GEMM is 200x64x64 (13 m-tiles),
// dense rows (no gather). S parked in LDS (XOR-slot swizzle); per-k epilogue
// adds b1[k], relu, dot w2sum. Softmax, ballot-pruned weighted ent gather,
// final linear. Separate BN kernel.

#define NDRUG 846
#define KNB   1024
#define NREL  200
#define BN_EPS 1e-5f

typedef __attribute__((ext_vector_type(8))) short short8;
typedef __attribute__((ext_vector_type(4))) float f32x4;

__device__ __forceinline__ unsigned short f2bf(float x){
    unsigned u = __float_as_uint(x);
    unsigned r = u + 0x7fffu + ((u >> 16) & 1u);
    return (unsigned short)(r >> 16);
}
__device__ __forceinline__ float bf2f(unsigned short h){
    return __uint_as_float(((unsigned)h) << 16);
}

__global__ void b2sum_kernel(const float* __restrict__ b2, float* __restrict__ b2s){
    int k = blockIdx.x*256 + threadIdx.x;
    const float4* p = (const float4*)(b2 + (size_t)k*64);
    float s = 0.f;
    #pragma unroll
    for (int i = 0; i < 16; ++i){ float4 v = p[i]; s += v.x+v.y+v.z+v.w; }
    b2s[k] = s;
}

__global__ __launch_bounds__(256,2) void fused_gnn(
    const float* __restrict__ drug_table, const float* __restrict__ rela_table,
    const float* __restrict__ ent_table,  const float* __restrict__ W1,
    const float* __restrict__ b1,         const float* __restrict__ W2,
    const float* __restrict__ lin_w,      const float* __restrict__ lin_b,
    const int* __restrict__ drug_name,    const int* __restrict__ adj_tail,
    const int* __restrict__ adj_rel,      const float* __restrict__ b2sum,
    float* __restrict__ y_out)
{
    __shared__ unsigned short Bh[4096], Bl[4096];   // W1 hi/lo, fragment-linear
    __shared__ __align__(16) float sS[13312];        // S[208][64], slot-XOR swizzle
    __shared__ __align__(16) float scores[KNB];
    __shared__ f32x4 w2s4[16];                       // w2sum as 16 x f32x4
    __shared__ float drug[64];
    __shared__ float red[256];
    __shared__ float wepart[4][64];
    __shared__ float de[128];

    const int t = threadIdx.x;
    const int lane = t & 63;
    const int w = t >> 6;
    const int lg = lane >> 4;
    const int l15 = lane & 15;
    const int n = blockIdx.x;

    if (t < 64) drug[t] = drug_table[(size_t)drug_name[n]*64 + t];

    { // w2sum partials: w2s[d] = sum_e W2[n,d,e]; thread t covers flat [16t,16t+16)
        const float4* W2v = (const float4*)(W2 + (size_t)n*4096);
        float s = 0.f;
        #pragma unroll
        for (int i = 0; i < 4; ++i){ float4 v = W2v[t*4+i]; s += v.x+v.y+v.z+v.w; }
        red[t] = s;
    }
    __syncthreads();
    if (t < 64) ((float*)w2s4)[t] = red[t*4]+red[t*4+1]+red[t*4+2]+red[t*4+3];

    { // stage W1 -> hi/lo bf16, fragment-linear layout for mfma_16x16x32 B-frags
        const float* W1n = W1 + (size_t)n*4096;
        #pragma unroll
        for (int p = 0; p < 16; ++p){
            int idx = p*256 + t;            // coalesced: d = idx>>6, e = idx&63
            float v = W1n[idx];
            int d = idx >> 6, e = idx & 63;
            int ss = d >> 5, j = d & 7, lgb = (d >> 3) & 3;
            int ln = (lgb << 4) | (e & 15);
            int dst = (((ss<<2) | (e>>4))*64 + ln)*8 + j;
            unsigned short h = f2bf(v);
            Bh[dst] = h;
            Bl[dst] = f2bf(v - bf2f(h));
        }
    }
    __syncthreads();

    // per-lane drug values at this lane's k-positions
    float dreg[2][8];
    #pragma unroll
    for (int ss = 0; ss < 2; ++ss)
        #pragma unroll
        for (int j = 0; j < 8; ++j)
            dreg[ss][j] = drug[ss*32 + (lg<<3) + j];

    // hoist all 16 B-fragments (hi+lo) to registers: reused by every m-tile
    short8 bhr[8], blr[8];
    #pragma unroll
    for (int f = 0; f < 8; ++f){
        bhr[f] = *(const short8*)&Bh[(f*64 + lane)*8];
        blr[f] = *(const short8*)&Bl[(f*64 + lane)*8];
    }

    // GEMM: S[r,:] = (drug . rela[r]) @ W1, r in [0,200), 13 m-tiles over 4 waves
    f32x4 acc[4][4] = {};
    float4 ra[4], rn[4];

    #define LOADT(mi_, dst) do {                                           \
        int mt_ = w + 4*(mi_);                                             \
        if (mt_ < 13){                                                     \
            int r_ = mt_*16 + l15; if (r_ > 199) r_ = 199;                 \
            const float* rp_ = rela_table + (size_t)r_*64 + (lg<<3);       \
            dst[0] = *(const float4*)rp_;       dst[1] = *(const float4*)(rp_+4);  \
            dst[2] = *(const float4*)(rp_+32);  dst[3] = *(const float4*)(rp_+36); \
        }                                                                  \
    } while(0)

    #define CVT2(va, vb, ss_, AH, AL) do {                                 \
        float xs_[8] = {(va).x,(va).y,(va).z,(va).w,(vb).x,(vb).y,(vb).z,(vb).w}; \
        _Pragma("unroll")                                                  \
        for (int j_ = 0; j_ < 8; ++j_){                                    \
            float x_ = xs_[j_] * dreg[ss_][j_];                            \
            unsigned short h_ = f2bf(x_);                                  \
            (AH)[j_] = (short)h_;                                          \
            (AL)[j_] = (short)f2bf(x_ - bf2f(h_));                         \
        }                                                                  \
    } while(0)

    LOADT(0, ra);

    #pragma unroll
    for (int mi = 0; mi < 4; ++mi){
        int mt = w + 4*mi;
        if (mt < 13){
            short8 Ah0, Al0, Ah1, Al1;
            CVT2(ra[0], ra[1], 0, Ah0, Al0);
            CVT2(ra[2], ra[3], 1, Ah1, Al1);
            if (mi < 3) LOADT(mi+1, rn);
            #pragma unroll
            for (int nn = 0; nn < 4; ++nn){
                acc[mi][nn] = __builtin_amdgcn_mfma_f32_16x16x32_bf16(Ah0, bhr[nn],   acc[mi][nn], 0,0,0);
                acc[mi][nn] = __builtin_amdgcn_mfma_f32_16x16x32_bf16(Ah0, blr[nn],   acc[mi][nn], 0,0,0);
                acc[mi][nn] = __builtin_amdgcn_mfma_f32_16x16x32_bf16(Al0, bhr[nn],   acc[mi][nn], 0,0,0);
                acc[mi][nn] = __builtin_amdgcn_mfma_f32_16x16x32_bf16(Ah1, bhr[4+nn], acc[mi][nn], 0,0,0);
                acc[mi][nn] = __builtin_amdgcn_mfma_f32_16x16x32_bf16(Ah1, blr[4+nn], acc[mi][nn], 0,0,0);
                acc[mi][nn] = __builtin_amdgcn_mfma_f32_16x16x32_bf16(Al1, bhr[4+nn], acc[mi][nn], 0,0,0);
            }
            #pragma unroll
            for (int q = 0; q < 4; ++q){ ra[q] = rn[q]; }
        }
    }

    // park S in LDS: word(r,e) = r*64 + ((e>>2 ^ (r&15))<<2) + (e&3)
    #pragma unroll
    for (int mi = 0; mi < 4; ++mi){
        int mt = w + 4*mi;
        if (mt < 13){
            int rb = mt*16 + (lg<<2);
            #pragma unroll
            for (int nn = 0; nn < 4; ++nn){
                int e = (nn<<4) | l15;
                int slot = e >> 2, wrd = e & 3;
                #pragma unroll
                for (int q = 0; q < 4; ++q){
                    int r = rb + q;
                    sS[r*64 + ((slot ^ (r & 15))<<2) + wrd] = acc[mi][nn][q];
                }
            }
        }
    }
    __syncthreads();

    // epilogue: score[k] = sum_e relu(S[arel[k],e] + b1[k,e]) * w2s[e]
    const int* arel = adj_rel + (size_t)n*KNB;
    int rr[4];
    float sc[4] = {0.f,0.f,0.f,0.f};
    #pragma unroll
    for (int i = 0; i < 4; ++i) rr[i] = arel[t + (i<<8)];

    #pragma unroll 2
    for (int e0 = 0; e0 < 16; ++e0){
        f32x4 wv = w2s4[e0];             // uniform -> LDS broadcast
        #pragma unroll
        for (int i = 0; i < 4; ++i){
            int k = t + (i<<8);
            f32x4 s4 = *(const f32x4*)&sS[rr[i]*64 + ((e0 ^ (rr[i] & 15))<<2)];
            f32x4 bq = *(const f32x4*)(b1 + (size_t)k*64 + (e0<<2));
            #pragma unroll
            for (int j = 0; j < 4; ++j)
                sc[i] += fmaxf(s4[j] + bq[j], 0.f) * wv[j];
        }
    }

    // block softmax over 1024 scores (+ b2sum)
    float sv[4]; float mx = -1e30f;
    #pragma unroll
    for (int i = 0; i < 4; ++i){
        sv[i] = sc[i] + b2sum[t + (i<<8)];
        mx = fmaxf(mx, sv[i]);
    }
    #pragma unroll
    for (int off = 1; off < 64; off <<= 1) mx = fmaxf(mx, __shfl_xor(mx, off, 64));
    if (lane == 0) red[w] = mx;
    __syncthreads();
    mx = fmaxf(fmaxf(red[0], red[1]), fmaxf(red[2], red[3]));
    float ps = 0.f;
    #pragma unroll
    for (int i = 0; i < 4; ++i){
        float e = __expf(sv[i] - mx);
        scores[t + (i<<8)] = e;
        ps += e;
    }
    #pragma unroll
    for (int off = 1; off < 64; off <<= 1) ps += __shfl_xor(ps, off, 64);
    if (lane == 0) red[8 + w] = ps;
    __syncthreads();
    float inv = 1.f / (red[8]+red[9]+red[10]+red[11]);

    // weighted entity gather, ballot-pruned (most exp underflow to exact 0)
    const int* atail = adj_tail + (size_t)n*KNB;
    const int kw = w << 8;
    float awe = 0.f;
    {
        f32x4 sg = *(const f32x4*)&scores[kw + (lane<<2)];
        bool nz = (sg[0]!=0.f) | (sg[1]!=0.f) | (sg[2]!=0.f) | (sg[3]!=0.f);
        unsigned long long msk = __ballot(nz);
        while (msk){
            int b = __ffsll((unsigned long long)msk) - 1;
            msk &= msk - 1;
            int kb2 = kw + (b<<2);
            #pragma unroll
            for (int j = 0; j < 4; ++j){
                float ev = scores[kb2 + j];     // uniform broadcast
                if (ev != 0.f)
                    awe += ev * ent_table[(size_t)atail[kb2+j]*64 + lane];
            }
        }
    }
    wepart[w][lane] = awe;
    __syncthreads();
    if (t < 64){
        de[t]    = (wepart[0][t]+wepart[1][t]+wepart[2][t]+wepart[3][t]) * inv;
        de[64+t] = drug[t];
    }
    __syncthreads();

    // y[j] = relu(lin_b[j] + sum_i de[i]*lin_w[j,i]); wave w covers i in [32w,32w+32)
    float yp = 0.f;
    #pragma unroll
    for (int ii = 0; ii < 32; ++ii){
        int i = w*32 + ii;
        yp += de[i] * lin_w[lane*128 + i];
    }
    red[t] = yp;
    __syncthreads();
    if (t < 64){
        float yv = lin_b[t] + red[t] + red[64+t] + red[128+t] + red[192+t];
        y_out[(size_t)n*64 + t] = fmaxf(yv, 0.f);
    }
}

__global__ void bn_kernel(const float* __restrict__ y, const float* __restrict__ bn_w,
                          const float* __restrict__ bn_b, float* __restrict__ out){
    __shared__ float r1[4], r2[4];
    const int j = blockIdx.x;
    const int t = threadIdx.x;
    float s1 = 0.f, s2 = 0.f;
    for (int i = t; i < NDRUG; i += 256){
        float v = y[(size_t)i*64 + j];
        s1 += v; s2 += v*v;
    }
    #pragma unroll
    for (int off = 1; off < 64; off <<= 1){
        s1 += __shfl_xor(s1, off, 64);
        s2 += __shfl_xor(s2, off, 64);
    }
    int w = t >> 6, lane = t & 63;
    if (lane == 0){ r1[w] = s1; r2[w] = s2; }
    __syncthreads();
    s1 = r1[0]+r1[1]+r1[2]+r1[3];
    s2 = r2[0]+r2[1]+r2[2]+r2[3];
    float mean = s1 * (1.f/NDRUG);
    float var  = s2 * (1.f/NDRUG) - mean*mean;   // biased (training-mode) variance
    float sc = rsqrtf(var + BN_EPS) * bn_w[j];
    float sh = bn_b[j] - mean*sc;
    for (int i = t; i < NDRUG; i += 256)
        out[(size_t)i*64 + j] = y[(size_t)i*64 + j]*sc + sh;
}

extern "C" void kernel_launch(void* const* d_in, const int* in_sizes, int n_in,
                              void* d_out, int out_size, void* d_ws, size_t ws_size,
                              hipStream_t stream) {
    const float* drug_table = (const float*)d_in[0];
    const float* rela_table = (const float*)d_in[1];
    const float* ent_table  = (const float*)d_in[2];
    const float* W1    = (const float*)d_in[3];
    const float* b1    = (const float*)d_in[4];
    const float* W2    = (const float*)d_in[5];
    const float* b2    = (const float*)d_in[6];
    const float* lin_w = (const float*)d_in[7];
    const float* lin_b = (const float*)d_in[8];
    const float* bn_w  = (const float*)d_in[9];
    const float* bn_b  = (const float*)d_in[10];
    const int* drug_name = (const int*)d_in[11];
    const int* adj_tail  = (const int*)d_in[12];
    const int* adj_rel   = (const int*)d_in[13];
    float* out = (float*)d_out;

    float* b2s = (float*)d_ws;          // [1024]
    float* yb  = b2s + KNB;             // [846*64]

    b2sum_kernel<<<KNB/256, 256, 0, stream>>>(b2, b2s);
    fused_gnn<<<NDRUG, 256, 0, stream>>>(drug_table, rela_table, ent_table, W1, b1, W2,
                                         lin_w, lin_b, drug_name, adj_tail, adj_rel, b2s, yb);
    bn_kernel<<<64, 256, 0, stream>>>(yb, bn_w, bn_b, out);
}

// Round 4
// 65.787 us; speedup vs baseline: 3.3290x; 1.1565x over previous
//
#include <hip/hip_runtime.h>

// GNN1: drug-relation GNN layer, MI355X (gfx950).
//   b2sum_kernel : b2sum[k] = sum_e b2[k,e]
//   gnn_a        : per-drug: w2sum, W1 hi/lo split, 200x64x64 split-bf16 MFMA
//                  GEMM -> S in LDS (XOR swizzle), coalesced b1-epilogue ->
//                  scores[n][k] (+b2sum) to ws.   LDS 51.7KB, 3 blocks/CU.
//   softgather   : softmax over K, deterministic compaction of nonzero
//                  weights, pipelined ent gather, final linear -> y.  6 blk/CU.
//   bn_kernel    : BatchNorm1d (training stats) over N=846 -> out.

#define NDRUG 846
#define KNB   1024
#define NREL  200
#define BN_EPS 1e-5f

typedef __attribute__((ext_vector_type(8))) short short8;
typedef __attribute__((ext_vector_type(4))) float f32x4;

__device__ __forceinline__ unsigned short f2bf(float x){
    unsigned u = __float_as_uint(x);
    unsigned r = u + 0x7fffu + ((u >> 16) & 1u);
    return (unsigned short)(r >> 16);
}
__device__ __forceinline__ float bf2f(unsigned short h){
    return __uint_as_float(((unsigned)h) << 16);
}

__global__ void b2sum_kernel(const float* __restrict__ b2, float* __restrict__ b2s){
    int k = blockIdx.x*256 + threadIdx.x;
    const float4* p = (const float4*)(b2 + (size_t)k*64);
    float s = 0.f;
    #pragma unroll
    for (int i = 0; i < 16; ++i){ float4 v = p[i]; s += v.x+v.y+v.z+v.w; }
    b2s[k] = s;
}

__global__ __launch_bounds__(256,3) void gnn_a(
    const float* __restrict__ drug_table, const float* __restrict__ rela_table,
    const float* __restrict__ W1,         const float* __restrict__ b1,
    const float* __restrict__ W2,         const int* __restrict__ drug_name,
    const int* __restrict__ adj_rel,      const float* __restrict__ b2s,
    float* __restrict__ scores_g)
{
    __shared__ __align__(16) float sS[12800];   // S[200][64] XOR-swizzled
    __shared__ __align__(16) float w2s[64];
    __shared__ float drug[64];
    unsigned short* Bh = (unsigned short*)sS;          // overlaid: dead after hoist
    unsigned short* Bl = (unsigned short*)(sS + 2048);

    const int t = threadIdx.x;
    const int lane = t & 63;
    const int w = t >> 6;
    const int lg = lane >> 4;
    const int l15 = lane & 15;
    const int n = blockIdx.x;

    if (t < 64) drug[t] = drug_table[(size_t)drug_name[n]*64 + t];

    { // w2s[d] = sum_e W2[n,d,e]; 4 lanes per d
        int d = t >> 2, q4 = t & 3;
        const f32x4* W2v = (const f32x4*)(W2 + (size_t)n*4096 + d*64 + q4*16);
        float s = 0.f;
        #pragma unroll
        for (int i = 0; i < 4; ++i){ f32x4 v = W2v[i]; s += v[0]+v[1]+v[2]+v[3]; }
        s += __shfl_xor(s, 1);
        s += __shfl_xor(s, 2);
        if (q4 == 0) w2s[d] = s;
    }

    { // stage W1 -> hi/lo bf16, fragment-linear for mfma_16x16x32 B-frags
        const float* W1n = W1 + (size_t)n*4096;
        #pragma unroll
        for (int p = 0; p < 16; ++p){
            int idx = p*256 + t;            // coalesced: d = idx>>6, e = idx&63
            float v = W1n[idx];
            int d = idx >> 6, e = idx & 63;
            int ss = d >> 5, j = d & 7, lgb = (d >> 3) & 3;
            int ln = (lgb << 4) | (e & 15);
            int dst = (((ss<<2) | (e>>4))*64 + ln)*8 + j;
            unsigned short h = f2bf(v);
            Bh[dst] = h;
            Bl[dst] = f2bf(v - bf2f(h));
        }
    }
    __syncthreads();

    float dreg[2][8];
    #pragma unroll
    for (int ss = 0; ss < 2; ++ss)
        #pragma unroll
        for (int j = 0; j < 8; ++j)
            dreg[ss][j] = drug[ss*32 + (lg<<3) + j];

    // hoist all 16 B-fragments (hi+lo) to registers
    short8 bhr[8], blr[8];
    #pragma unroll
    for (int f = 0; f < 8; ++f){
        bhr[f] = *(const short8*)&Bh[(f*64 + lane)*8];
        blr[f] = *(const short8*)&Bl[(f*64 + lane)*8];
    }
    __syncthreads();   // Bh/Bl dead; sS may now be overwritten

    float4 ra[4], rn[4];
    #define LOADT(mi_, dst) do {                                           \
        int mt_ = w + 4*(mi_);                                             \
        if (mt_ < 13){                                                     \
            int r_ = mt_*16 + l15; if (r_ > 199) r_ = 199;                 \
            const float* rp_ = rela_table + (size_t)r_*64 + (lg<<3);       \
            dst[0] = *(const float4*)rp_;       dst[1] = *(const float4*)(rp_+4);  \
            dst[2] = *(const float4*)(rp_+32);  dst[3] = *(const float4*)(rp_+36); \
        }                                                                  \
    } while(0)

    #define CVT2(va, vb, ss_, AH, AL) do {                                 \
        float xs_[8] = {(va).x,(va).y,(va).z,(va).w,(vb).x,(vb).y,(vb).z,(vb).w}; \
        _Pragma("unroll")                                                  \
        for (int j_ = 0; j_ < 8; ++j_){                                    \
            float x_ = xs_[j_] * dreg[ss_][j_];                            \
            unsigned short h_ = f2bf(x_);                                  \
            (AH)[j_] = (short)h_;                                          \
            (AL)[j_] = (short)f2bf(x_ - bf2f(h_));                         \
        }                                                                  \
    } while(0)

    LOADT(0, ra);

    #pragma unroll 1
    for (int mi = 0; mi < 4; ++mi){
        int mt = w + 4*mi;
        if (mt < 13){
            short8 Ah0, Al0, Ah1, Al1;
            CVT2(ra[0], ra[1], 0, Ah0, Al0);
            CVT2(ra[2], ra[3], 1, Ah1, Al1);
            if (mi < 3) LOADT(mi+1, rn);
            f32x4 acc[4] = {};
            #pragma unroll
            for (int nn = 0; nn < 4; ++nn){
                acc[nn] = __builtin_amdgcn_mfma_f32_16x16x32_bf16(Ah0, bhr[nn],   acc[nn], 0,0,0);
                acc[nn] = __builtin_amdgcn_mfma_f32_16x16x32_bf16(Ah0, blr[nn],   acc[nn], 0,0,0);
                acc[nn] = __builtin_amdgcn_mfma_f32_16x16x32_bf16(Al0, bhr[nn],   acc[nn], 0,0,0);
                acc[nn] = __builtin_amdgcn_mfma_f32_16x16x32_bf16(Ah1, bhr[4+nn], acc[nn], 0,0,0);
                acc[nn] = __builtin_amdgcn_mfma_f32_16x16x32_bf16(Ah1, blr[4+nn], acc[nn], 0,0,0);
                acc[nn] = __builtin_amdgcn_mfma_f32_16x16x32_bf16(Al1, bhr[4+nn], acc[nn], 0,0,0);
            }
            // park: word(r,e) = r*64 + ((e>>2 ^ (r&15))<<2) + (e&3)
            int rb = mt*16 + (lg<<2);
            #pragma unroll
            for (int nn = 0; nn < 4; ++nn){
                int e = (nn<<4) | l15;
                int slot = e >> 2, wrd = e & 3;
                #pragma unroll
                for (int q = 0; q < 4; ++q){
                    int r = rb + q;
                    if (r < 200)
                        sS[r*64 + ((slot ^ (r & 15))<<2) + wrd] = acc[nn][q];
                }
            }
            #pragma unroll
            for (int q = 0; q < 4; ++q){ ra[q] = rn[q]; }
        }
    }
    __syncthreads();

    // epilogue: score[k] = sum_e relu(S[arel[k],e] + b1[k,e]) * w2s[e] + b2s[k]
    // 4 lanes per k (ec = lane&3 covers 16 e's); b1 reads contiguous per wave.
    const int* arel = adj_rel + (size_t)n*KNB;
    const int ec = lane & 3;
    f32x4 w2r[4];
    #pragma unroll
    for (int j = 0; j < 4; ++j) w2r[j] = *(const f32x4*)&w2s[ec*16 + j*4];

    #pragma unroll 2
    for (int pass = 0; pass < 16; ++pass){
        int k = pass*64 + w*16 + (lane >> 2);
        int rr = arel[k];
        const float* b1p = b1 + (size_t)k*64 + ec*16;
        float sc = 0.f;
        #pragma unroll
        for (int j = 0; j < 4; ++j){
            int slot = ec*4 + j;
            f32x4 s4 = *(const f32x4*)&sS[rr*64 + ((slot ^ (rr & 15))<<2)];
            f32x4 bq = *(const f32x4*)(b1p + 4*j);
            #pragma unroll
            for (int q = 0; q < 4; ++q)
                sc += fmaxf(s4[q] + bq[q], 0.f) * w2r[j][q];
        }
        sc += __shfl_xor(sc, 1);
        sc += __shfl_xor(sc, 2);
        if (ec == 0) scores_g[(size_t)n*KNB + k] = sc + b2s[k];
    }
}

__global__ __launch_bounds__(256,6) void softgather(
    const float* __restrict__ scores_g, const int* __restrict__ adj_tail,
    const float* __restrict__ ent_table, const float* __restrict__ drug_table,
    const int* __restrict__ drug_name,   const float* __restrict__ lin_w,
    const float* __restrict__ lin_b,     float* __restrict__ y_out)
{
    __shared__ float sE[KNB];
    __shared__ int list[KNB];
    __shared__ int segc[17];
    __shared__ float red[256];
    __shared__ float wepart[4][64];
    __shared__ float de[128];

    const int t = threadIdx.x;
    const int lane = t & 63;
    const int w = t >> 6;
    const int n = blockIdx.x;

    float dpre = 0.f;
    if (t < 64) dpre = drug_table[(size_t)drug_name[n]*64 + t];

    const float* sg = scores_g + (size_t)n*KNB;
    float sv[4]; float mx = -1e30f;
    #pragma unroll
    for (int i = 0; i < 4; ++i){
        sv[i] = sg[t + (i<<8)];
        mx = fmaxf(mx, sv[i]);
    }
    #pragma unroll
    for (int off = 1; off < 64; off <<= 1) mx = fmaxf(mx, __shfl_xor(mx, off, 64));
    if (lane == 0) red[w] = mx;
    __syncthreads();
    mx = fmaxf(fmaxf(red[0], red[1]), fmaxf(red[2], red[3]));
    float ei[4]; float ps = 0.f;
    #pragma unroll
    for (int i = 0; i < 4; ++i){
        ei[i] = __expf(sv[i] - mx);
        sE[t + (i<<8)] = ei[i];
        ps += ei[i];
    }
    #pragma unroll
    for (int off = 1; off < 64; off <<= 1) ps += __shfl_xor(ps, off, 64);
    if (lane == 0) red[8 + w] = ps;
    __syncthreads();
    const float inv = 1.f / (red[8]+red[9]+red[10]+red[11]);

    // deterministic compaction of nonzero-weight k's (ordered by k)
    unsigned long long bal[4]; int pos[4];
    #pragma unroll
    for (int i = 0; i < 4; ++i){
        bool nz = (ei[i] != 0.f);
        bal[i] = __ballot(nz);
        pos[i] = (int)__popcll(bal[i] & ((1ull << lane) - 1ull));
        if (lane == 0) segc[i*4 + w] = (int)__popcll(bal[i]);
    }
    __syncthreads();
    if (t == 0){
        int acc = 0;
        #pragma unroll
        for (int s = 0; s < 16; ++s){ int c = segc[s]; segc[s] = acc; acc += c; }
        segc[16] = acc;
    }
    __syncthreads();
    #pragma unroll
    for (int i = 0; i < 4; ++i){
        if (ei[i] != 0.f)
            list[segc[i*4 + w] + pos[i]] = (i<<8) + (w<<6) + lane;
    }
    const int C = segc[16];
    __syncthreads();

    // pipelined gather over compacted list (wave-strided)
    const int* atail = adj_tail + (size_t)n*KNB;
    float awe = 0.f;
    {
        int j = w;
        float ev0 = 0.f, row0 = 0.f;
        if (j < C){
            int k0 = list[j];
            ev0 = sE[k0];
            row0 = ent_table[(size_t)atail[k0]*64 + lane];
        }
        while (j < C){
            int jn = j + 4;
            float ev1 = 0.f, row1 = 0.f;
            if (jn < C){
                int k1 = list[jn];
                ev1 = sE[k1];
                row1 = ent_table[(size_t)atail[k1]*64 + lane];
            }
            awe += ev0 * row0;
            ev0 = ev1; row0 = row1; j = jn;
        }
    }
    wepart[w][lane] = awe;
    __syncthreads();
    if (t < 64){
        de[t]    = (wepart[0][t]+wepart[1][t]+wepart[2][t]+wepart[3][t]) * inv;
        de[64+t] = dpre;
    }
    __syncthreads();

    // y[j] = relu(lin_b[j] + sum_i de[i]*lin_w[j,i]); wave w covers i in [32w,32w+32)
    float yp = 0.f;
    #pragma unroll
    for (int ii = 0; ii < 32; ++ii){
        int i = w*32 + ii;
        yp += de[i] * lin_w[lane*128 + i];
    }
    red[t] = yp;
    __syncthreads();
    if (t < 64){
        float yv = lin_b[t] + red[t] + red[64+t] + red[128+t] + red[192+t];
        y_out[(size_t)n*64 + t] = fmaxf(yv, 0.f);
    }
}

__global__ void bn_kernel(const float* __restrict__ y, const float* __restrict__ bn_w,
                          const float* __restrict__ bn_b, float* __restrict__ out){
    __shared__ float r1[4], r2[4];
    const int j = blockIdx.x;
    const int t = threadIdx.x;
    float s1 = 0.f, s2 = 0.f;
    for (int i = t; i < NDRUG; i += 256){
        float v = y[(size_t)i*64 + j];
        s1 += v; s2 += v*v;
    }
    #pragma unroll
    for (int off = 1; off < 64; off <<= 1){
        s1 += __shfl_xor(s1, off, 64);
        s2 += __shfl_xor(s2, off, 64);
    }
    int w = t >> 6, lane = t & 63;
    if (lane == 0){ r1[w] = s1; r2[w] = s2; }
    __syncthreads();
    s1 = r1[0]+r1[1]+r1[2]+r1[3];
    s2 = r2[0]+r2[1]+r2[2]+r2[3];
    float mean = s1 * (1.f/NDRUG);
    float var  = s2 * (1.f/NDRUG) - mean*mean;   // biased (training-mode) variance
    float sc = rsqrtf(var + BN_EPS) * bn_w[j];
    float sh = bn_b[j] - mean*sc;
    for (int i = t; i < NDRUG; i += 256)
        out[(size_t)i*64 + j] = y[(size_t)i*64 + j]*sc + sh;
}

extern "C" void kernel_launch(void* const* d_in, const int* in_sizes, int n_in,
                              void* d_out, int out_size, void* d_ws, size_t ws_size,
                              hipStream_t stream) {
    const float* drug_table = (const float*)d_in[0];
    const float* rela_table = (const float*)d_in[1];
    const float* ent_table  = (const float*)d_in[2];
    const float* W1    = (const float*)d_in[3];
    const float* b1    = (const float*)d_in[4];
    const float* W2    = (const float*)d_in[5];
    const float* b2    = (const float*)d_in[6];
    const float* lin_w = (const float*)d_in[7];
    const float* lin_b = (const float*)d_in[8];
    const float* bn_w  = (const float*)d_in[9];
    const float* bn_b  = (const float*)d_in[10];
    const int* drug_name = (const int*)d_in[11];
    const int* adj_tail  = (const int*)d_in[12];
    const int* adj_rel   = (const int*)d_in[13];
    float* out = (float*)d_out;

    float* b2s     = (float*)d_ws;                  // [1024]
    float* yb      = b2s + KNB;                     // [846*64]
    float* scoresg = yb + NDRUG*64;                 // [846*1024]

    b2sum_kernel<<<KNB/256, 256, 0, stream>>>(b2, b2s);
    gnn_a<<<NDRUG, 256, 0, stream>>>(drug_table, rela_table, W1, b1, W2,
                                     drug_name, adj_rel, b2s, scoresg);
    softgather<<<NDRUG, 256, 0, stream>>>(scoresg, adj_tail, ent_table, drug_table,
                                          drug_name, lin_w, lin_b, yb);
    bn_kernel<<<64, 256, 0, stream>>>(yb, bn_w, bn_b, out);
}